// Round 13
// baseline (126.828 us; speedup 1.0000x reference)
//
#include <hip/hip_runtime.h>
#include <hip/hip_bf16.h>
#include <math.h>

namespace {

constexpr int B  = 4;
constexpr int N  = 2048;
constexpr int F0 = 6;
constexpr int F  = 64;
constexpr int DK = 16;
constexpr float EPS = 1e-5f;
constexpr int MT2 = N / 32;  // 64 m-tiles (32 rows each)

typedef float fx4 __attribute__((ext_vector_type(4)));
typedef __attribute__((ext_vector_type(8)))  short bf16x8;
typedef __attribute__((ext_vector_type(4)))  short bf16x4;
typedef __attribute__((ext_vector_type(16))) float f32x16;

__device__ inline short f2bf(float x, float* xr) {
  __hip_bfloat16 h = __float2bfloat16(x);
  *xr = __bfloat162float(h);
  short s; __builtin_memcpy(&s, &h, 2);
  return s;
}
__device__ inline short f2bf(float x) {
  __hip_bfloat16 h = __float2bfloat16(x);
  short s; __builtin_memcpy(&s, &h, 2);
  return s;
}

// ---------------- weight-folding GEMMs -> bf16 operands ----------------
// z==0: T slice0 = W1·norm(X) (fp32)   z==1: Tbf = bf16(W2·norm(X))
// z==2: T slice1 = Wres·norm(X) (fp32) z==3: projbf = bf16(Ap·X) + sqnb
//        (layer 0: projbf = bf16(X/sigma) zero-padded to DK rows)
// Norm stats reconstructed from adjfull's 64 per-m-tile partials per row.
template<int FIN, bool NORM>
__global__ __launch_bounds__(256) void k_wx(const float* __restrict__ X,     // (B,FIN,N)
                                            const float* __restrict__ sigma, // layer0 only
                                            const float* __restrict__ ssum,  // (B*F,64)
                                            const float* __restrict__ ssq,
                                            const float* __restrict__ Wc,    // (64,2*FIN)
                                            const float* __restrict__ Wr,    // (64,FIN)
                                            const float* __restrict__ Ap,    // (DK,FIN) or null
                                            float* __restrict__ T,           // (B,2,64,N)
                                            short* __restrict__ Tbf,         // (B,64,N) bf16
                                            short* __restrict__ projbf,      // (B,DK,N) bf16
                                            float* __restrict__ sqnb) {      // (B,N)
  int z = blockIdx.z, b = blockIdx.y, n0 = blockIdx.x * 64;
  int t = threadIdx.x, n = t & 63, og = t >> 6;
  __shared__ float xS[64][FIN + 1];
  __shared__ __align__(16) float wT[FIN][68];
  __shared__ float mnS[64], rsS[64];
  __shared__ float sp[4][64];
  for (int e = t; e < FIN * 64; e += 256) {
    int f = e >> 6, nn = e & 63;
    xS[nn][f] = X[((size_t)b * FIN + f) * N + n0 + nn];
  }
  bool l0proj = (z == 3 && Ap == nullptr);
  if (!l0proj) {
    const float* base; int ld, off, OUT;
    if (z == 0)      { base = Wc; ld = 2 * FIN; off = 0;   OUT = 64; }
    else if (z == 1) { base = Wc; ld = 2 * FIN; off = FIN; OUT = 64; }
    else if (z == 2) { base = Wr; ld = FIN;     off = 0;   OUT = 64; }
    else             { base = Ap; ld = FIN;     off = 0;   OUT = DK; }
    for (int e = t; e < OUT * FIN; e += 256) {
      int o = e / FIN, f = e - o * FIN;
      wT[f][o] = base[(size_t)o * ld + off + f];
    }
  }
  if (NORM && z < 3 && t < 64) {
    int row = b * FIN + t;
    const fx4* s4 = (const fx4*)(ssum + (size_t)row * 64);
    const fx4* q4 = (const fx4*)(ssq + (size_t)row * 64);
    float S = 0.f, Q = 0.f;
#pragma unroll
    for (int p = 0; p < 16; ++p) {
      fx4 v = s4[p]; S += v[0] + v[1] + v[2] + v[3];
      fx4 u = q4[p]; Q += u[0] + u[1] + u[2] + u[3];
    }
    float mn = S / (float)N;
    mnS[t] = mn;
    rsS[t] = rsqrtf(Q / (float)N - mn * mn + EPS);
  }
  __syncthreads();
  if (z < 3) {
    float cacc[16] = {};
#pragma unroll 4
    for (int f = 0; f < FIN; ++f) {
      float x = xS[n][f];
      if (NORM) x = (x - mnS[f]) * rsS[f];
      fx4 w0 = *(const fx4*)&wT[f][og * 16 + 0];
      fx4 w1 = *(const fx4*)&wT[f][og * 16 + 4];
      fx4 w2 = *(const fx4*)&wT[f][og * 16 + 8];
      fx4 w3 = *(const fx4*)&wT[f][og * 16 + 12];
#pragma unroll
      for (int k = 0; k < 4; ++k) {
        cacc[k + 0]  = fmaf(w0[k], x, cacc[k + 0]);
        cacc[k + 4]  = fmaf(w1[k], x, cacc[k + 4]);
        cacc[k + 8]  = fmaf(w2[k], x, cacc[k + 8]);
        cacc[k + 12] = fmaf(w3[k], x, cacc[k + 12]);
      }
    }
    if (z == 1) {
#pragma unroll
      for (int k = 0; k < 16; ++k)
        Tbf[((size_t)b * 64 + og * 16 + k) * N + n0 + n] = f2bf(cacc[k]);
    } else {
      int sl = (z == 0) ? 0 : 1;
#pragma unroll
      for (int k = 0; k < 16; ++k)
        T[(((size_t)b * 2 + sl) * 64 + og * 16 + k) * N + n0 + n] = cacc[k];
    }
  } else {
    float r[4];
    if (Ap != nullptr) {
      float cacc[4] = {};
#pragma unroll 4
      for (int f = 0; f < FIN; ++f) {
        float x = xS[n][f];
        fx4 w0 = *(const fx4*)&wT[f][og * 4];
#pragma unroll
        for (int k = 0; k < 4; ++k) cacc[k] = fmaf(w0[k], x, cacc[k]);
      }
#pragma unroll
      for (int k = 0; k < 4; ++k) {
        short hs = f2bf(cacc[k], &r[k]);
        projbf[((size_t)b * DK + og * 4 + k) * N + n0 + n] = hs;
      }
    } else {
      float inv = 1.f / sigma[0];
#pragma unroll
      for (int k = 0; k < 4; ++k) {
        int d = og * 4 + k;
        float v = (d < F0) ? xS[n][d] * inv : 0.f;
        short hs = f2bf(v, &r[k]);
        projbf[((size_t)b * DK + d) * N + n0 + n] = hs;
      }
    }
    float s = 0.f;
#pragma unroll
    for (int k = 0; k < 4; ++k) s = fmaf(r[k], r[k], s);
    sp[og][n] = s;
    __syncthreads();
    if (t < 64) sqnb[(size_t)b * N + n0 + t] = sp[0][t] + sp[1][t] + sp[2][t] + sp[3][t];
  }
}

// ---------------- full-N adjacency+deg+PV+epilogue (nch=1, fused gopconv tail) ----------------
// Block: 32-m-tile × full N (16 iters of 128 n). 4 waves:
//   gram: wave w = n-quadrant w (32 n)     PV: wave (fq=w&1, kh=w>>1) = f-half × n-half
// Tail: cross-wave K-reduce acc, deg sum, gopconv epilogue, emb write, stat partials.
__global__ __launch_bounds__(256) void k_adjfull(const short* __restrict__ projbf,
                                                 const float* __restrict__ sqnb,
                                                 const short* __restrict__ Tbf,
                                                 const float* __restrict__ T,    // (B,2,64,N)
                                                 const float* __restrict__ bias,
                                                 const float* __restrict__ bres,
                                                 float* __restrict__ out,        // (B,64,N)
                                                 float* __restrict__ ssum,       // (B*F,64)
                                                 float* __restrict__ ssq) {
  int bid = blockIdx.x;
  int mtile = bid & 63, b = bid >> 6;
  int M0 = mtile * 32;
  int t = threadIdx.x, w = t >> 6, l = t & 63;
  int l31 = l & 31, lh = l >> 5;
  int fq = w & 1, kh = w >> 1;

  const short* pb = projbf + (size_t)b * DK * N;
  const short* vb = Tbf + (size_t)b * F * N;
  const float* sq = sqnb + (size_t)b * N;

  __shared__ __align__(16) short adjT[2][32][132];  // [m][n] bf16, pad132: 2-way banks
  __shared__ __align__(16) short vS[2][64][132];    // [f][n] bf16
  __shared__ float sqmS[32];
  __shared__ float degS[4][32];
  __shared__ float accS[2][32][33];

  // A-frag (m-tile) + m-norms, once
  bf16x8 afrag;
#pragma unroll
  for (int j = 0; j < 8; ++j)
    afrag[j] = pb[(size_t)(lh * 8 + j) * N + M0 + l31];
  if (t < 32) sqmS[t] = sq[M0 + t];
  __syncthreads();
  float sqmr[16];
#pragma unroll
  for (int r = 0; r < 16; ++r)
    sqmr[r] = sqmS[(r & 3) + 8 * (r >> 2) + 4 * lh];

  f32x16 acc;
#pragma unroll
  for (int r = 0; r < 16; ++r) acc[r] = 0.f;
  float pdm[16];
#pragma unroll
  for (int r = 0; r < 16; ++r) pdm[r] = 0.f;

  int buf = 0;
  for (int nt = 0; nt < N; nt += 128) {
    {  // stage V tile (64 f × 128 n bf16) into vS[buf]
      int f = t >> 2, nc = (t & 3) * 32;
#pragma unroll
      for (int jj = 0; jj < 8; ++jj)
        *(bf16x4*)&vS[buf][f][nc + 4 * jj] =
            *(const bf16x4*)&vb[(size_t)f * N + nt + nc + 4 * jj];
    }
    // gram B-frag for this wave's 32-n quadrant (direct from global, L2-hot)
    bf16x8 bfrag;
    int bn = nt + w * 32 + l31;
#pragma unroll
    for (int j = 0; j < 8; ++j)
      bfrag[j] = pb[(size_t)(lh * 8 + j) * N + bn];
    float sqn_v = sq[bn];
    f32x16 gz;
#pragma unroll
    for (int r = 0; r < 16; ++r) gz[r] = 0.f;
    f32x16 g = __builtin_amdgcn_mfma_f32_32x32x16_bf16(afrag, bfrag, gz, 0, 0, 0);
#pragma unroll
    for (int r = 0; r < 16; ++r) {
      int m = (r & 3) + 8 * (r >> 2) + 4 * lh;
      float dist = fmaxf(sqmr[r] + sqn_v - 2.f * g[r], 0.f);
      float a = __expf(-dist);
      pdm[r] += a;
      adjT[buf][m][w * 32 + l31] = f2bf(a);
    }
    __syncthreads();  // adjT[buf]/vS[buf] complete; prev buffer's readers also done
    // PV: wave (fq,kh): acc[f in fq-half][m] over n in kh-half (4 K-steps)
#pragma unroll
    for (int ks = 0; ks < 4; ++ks) {
      int nb = kh * 64 + ks * 16 + lh * 8;
      bf16x4 alo = *(const bf16x4*)&vS[buf][fq * 32 + l31][nb];
      bf16x4 ahi = *(const bf16x4*)&vS[buf][fq * 32 + l31][nb + 4];
      bf16x4 blo = *(const bf16x4*)&adjT[buf][l31][nb];
      bf16x4 bhi = *(const bf16x4*)&adjT[buf][l31][nb + 4];
      bf16x8 af2, bf2;
#pragma unroll
      for (int i2 = 0; i2 < 4; ++i2) {
        af2[i2] = alo[i2]; af2[i2 + 4] = ahi[i2];
        bf2[i2] = blo[i2]; bf2[i2 + 4] = bhi[i2];
      }
      acc = __builtin_amdgcn_mfma_f32_32x32x16_bf16(af2, bf2, acc, 0, 0, 0);
    }
    buf ^= 1;
  }
  // deg partials: reduce each wave's pdm over its 32 n-cols (l31)
#pragma unroll
  for (int r = 0; r < 16; ++r) {
    pdm[r] += __shfl_xor(pdm[r], 1);
    pdm[r] += __shfl_xor(pdm[r], 2);
    pdm[r] += __shfl_xor(pdm[r], 4);
    pdm[r] += __shfl_xor(pdm[r], 8);
    pdm[r] += __shfl_xor(pdm[r], 16);
  }
  if (l31 == 0) {
#pragma unroll
    for (int r = 0; r < 16; ++r)
      degS[w][(r & 3) + 8 * (r >> 2) + 4 * lh] = pdm[r];
  }
  // cross-wave PV K-reduction: kh=1 deposits, kh=0 accumulates
  if (kh == 1) {
#pragma unroll
    for (int r = 0; r < 16; ++r) accS[fq][lh * 16 + r][l31] = acc[r];
  }
  __syncthreads();
  if (kh == 0) {
#pragma unroll
    for (int r = 0; r < 16; ++r) acc[r] += accS[fq][lh * 16 + r][l31];
    float dgm = degS[0][l31] + degS[1][l31] + degS[2][l31] + degS[3][l31];
    const float* T0 = T + ((size_t)b * 2 + 0) * 64 * N;
    const float* T2 = T + ((size_t)b * 2 + 1) * 64 * N;
#pragma unroll
    for (int r = 0; r < 16; ++r) {
      int o = fq * 32 + (r & 3) + 8 * (r >> 2) + 4 * lh;
      float t0 = T0[(size_t)o * N + M0 + l31];
      float t2 = T2[(size_t)o * N + M0 + l31];
      float ov = fmaxf(acc[r] + t0 * dgm + bias[o], 0.f) + t2 + bres[o];
      out[((size_t)b * 64 + o) * N + M0 + l31] = ov;
      float ps = ov, pq = ov * ov;
      ps += __shfl_xor(ps, 1);  pq += __shfl_xor(pq, 1);
      ps += __shfl_xor(ps, 2);  pq += __shfl_xor(pq, 2);
      ps += __shfl_xor(ps, 4);  pq += __shfl_xor(pq, 4);
      ps += __shfl_xor(ps, 8);  pq += __shfl_xor(pq, 8);
      ps += __shfl_xor(ps, 16); pq += __shfl_xor(pq, 16);
      if (l31 == 0) {
        ssum[((size_t)b * 64 + o) * MT2 + mtile] = ps;
        ssq [((size_t)b * 64 + o) * MT2 + mtile] = pq;
      }
    }
  }
}

// ---------------- readout from adjfull partials ----------------
__global__ __launch_bounds__(256) void k_readout(const float* __restrict__ ssum,
                                                 const float* __restrict__ fw,
                                                 const float* __restrict__ fb,
                                                 float* __restrict__ out) {
  int t = threadIdx.x, b = t >> 6, l = t & 63;
  int row = b * 64 + l;
  const fx4* s4 = (const fx4*)(ssum + (size_t)row * 64);
  float po = 0.f;
#pragma unroll
  for (int p = 0; p < 16; ++p) {
    fx4 v = s4[p];
    po += v[0] + v[1] + v[2] + v[3];
  }
  po /= (float)N;
  float mn = po;
#pragma unroll
  for (int off = 1; off < 64; off <<= 1) mn += __shfl_xor(mn, off);
  mn *= (1.f / 64.f);
  float d = po - mn;
  float var = d * d;
#pragma unroll
  for (int off = 1; off < 64; off <<= 1) var += __shfl_xor(var, off);
  var *= (1.f / 64.f);
  float rs = rsqrtf(var + EPS);
  float lg = d * rs * fw[l];
#pragma unroll
  for (int off = 1; off < 64; off <<= 1) lg += __shfl_xor(lg, off);
  if (l == 0) out[b] = 1.f / (1.f + __expf(-(lg + fb[0])));
}

}  // namespace

extern "C" void kernel_launch(void* const* d_in, const int* in_sizes, int n_in,
                              void* d_out, int out_size, void* d_ws, size_t ws_size,
                              hipStream_t stream) {
  const float* emb_in   = (const float*)d_in[0];
  const float* sigma    = (const float*)d_in[1];
  const float* fst_w    = (const float*)d_in[2];
  const float* fst_b    = (const float*)d_in[3];
  const float* fst_wres = (const float*)d_in[4];
  const float* fst_bres = (const float*)d_in[5];
  const float* adj_proj = (const float*)d_in[6];
  const float* w        = (const float*)d_in[7];
  const float* bw       = (const float*)d_in[8];
  const float* wres     = (const float*)d_in[9];
  const float* bres     = (const float*)d_in[10];
  const float* fcl_w    = (const float*)d_in[11];
  const float* fcl_b    = (const float*)d_in[12];

  float* ws = (float*)d_ws;
  float* embA  = ws;  ws += (size_t)B * F * N;
  float* embB  = ws;  ws += (size_t)B * F * N;
  float* T     = ws;  ws += 2 * (size_t)B * F * N;
  short* Tbf   = (short*)ws;  ws += (size_t)B * F * N / 2;
  short* projbf = (short*)ws; ws += (size_t)B * DK * N / 2;
  float* sqnb  = ws;  ws += (size_t)B * N;
  float* ssum  = ws;  ws += (size_t)B * F * MT2;
  float* ssq   = ws;  ws += (size_t)B * F * MT2;

  // ---- layer 0 ----
  k_wx<F0, false><<<dim3(N / 64, B, 4), 256, 0, stream>>>(
      emb_in, sigma, nullptr, nullptr, fst_w, fst_wres, nullptr, T, Tbf, projbf, sqnb);
  k_adjfull<<<dim3(MT2 * B), 256, 0, stream>>>(projbf, sqnb, Tbf, T, fst_b, fst_bres,
                                               embA, ssum, ssq);

  // ---- layers 1..2 ----
  const float* src = embA;
  float* dst = embB;
  for (int i = 0; i < 2; ++i) {
    k_wx<F, true><<<dim3(N / 64, B, 4), 256, 0, stream>>>(
        src, nullptr, ssum, ssq, w + (size_t)i * F * 2 * F, wres + (size_t)i * F * F,
        adj_proj + (size_t)i * DK * F, T, Tbf, projbf, sqnb);
    k_adjfull<<<dim3(MT2 * B), 256, 0, stream>>>(projbf, sqnb, Tbf, T, bw + (size_t)i * F,
                                                 bres + (size_t)i * F, dst, ssum, ssq);
    float* tmp = (float*)src;
    src = dst;
    dst = tmp;
  }

  k_readout<<<dim3(1), 256, 0, stream>>>(ssum, fcl_w, fcl_b, (float*)d_out);
}